// Round 1
// baseline (5239.407 us; speedup 1.0000x reference)
//
#include <hip/hip_runtime.h>

// PairmixLayer: out[n,f,l3²+c] = Σ_{l1,l2} (Σ_k W[idx,f,k] g[n,k]) · Σ_{a,b} x[n,f,l1²+a] y[n,f,l2²+b] cg[l1,l2,l3,a,b,c]
// N=150000, F=64, K=16. fp32 (no fp32 MFMA -> VALU kernel).
// R2 vs R1:
//  - Dropped sx/sy LDS staging (direct per-lane 36B AoS reads, L1-served) -> LDS 37.4->18.4 KB,
//    occupancy LDS limit 4 -> 8 blocks/CU. Only out-staging remains in LDS (coalesced final store).
//  - l3-split phase1: m[2][9] (18 regs) per l3 slice instead of m[2][27]=54 -> kills the spill
//    seen as +310MB WRITE_SIZE surplus in R1.
//  - Phase-2 loop order (a,b outer, c inner): p[5][5] (25 regs) -> single scalar pb.
//  - g[2][16] moved to wave-uniform SGPRs via v_readlane (n rows are wave-uniform at TPW=2).
//  - W relaid out [l3][l1*3+l2][f][k]: per-lane k-contiguous -> 108 dwordx4 loads/wave vs 432 dword.

#define NTOT   150000
#define FDIM   64
#define KDIM   16
#define TPW    2            // n per wave (W-table L2 traffic amortization)
#define NPB    8            // n per block (4 waves)

__device__ __constant__ float c_binom[16] = {
    1.f, 15.f, 105.f, 455.f, 1365.f, 3003.f, 5005.f, 6435.f,
    6435.f, 5005.f, 3003.f, 1365.f, 455.f, 105.f, 15.f, 1.f };

// ws: Wt[l3][l1*3+l2][f][k]  (27*64*16 floats = 110592 B), k contiguous per (f) lane
__global__ void transpose_w(const float* __restrict__ w, float* __restrict__ wt) {
    int t = blockIdx.x * 256 + threadIdx.x;          // 27648 = 108*256 exact
    if (t >= 27 * FDIM * KDIM) return;
    int k = t & 15, f = (t >> 4) & 63, idx = t >> 10;       // idx = l1*9 + l2*3 + l3
    int l1 = idx / 9, l2 = (idx % 9) / 3, l3 = idx % 3;
    int nidx = l3 * 9 + l1 * 3 + l2;
    wt[nidx * 1024 + f * 16 + k] = w[t];
}

__global__ __launch_bounds__(256, 6)   // VGPR budget ~84: room for m[18]+xv/yv[36]+temps, no spill
void pairmix_main(const float* __restrict__ x, const float* __restrict__ y,
                  const float* __restrict__ r, const float* __restrict__ cg,
                  const float* __restrict__ wt, float* __restrict__ out)
{
    __shared__ __align__(16) float so[4][TPW * FDIM * 9];   // out staging: 18432 B/block

    const int tid  = threadIdx.x;
    const int w    = tid >> 6;
    const int lane = tid & 63;                 // = f
    const int nw   = blockIdx.x * NPB + w * TPW;

    // ---- Bernstein g for both n rows -> wave-uniform scalars (SGPRs) via readlane ----
    float gvv;
    {
        const int j = (lane >> 4) & 1, k = lane & 15;   // lanes 0..31 carry the real values
        float u = r[nw + j] * 0.2f;
        u = fminf(fmaxf(u, 0.0f), 1.0f);
        float a = 1.0f, b = 1.0f;
        for (int i = 0; i < k; ++i)            a *= u;
        for (int i = 0; i < KDIM - 1 - k; ++i) b *= (1.0f - u);
        gvv = c_binom[k] * a * b;
    }
    float g0[16], g1[16];
#pragma unroll
    for (int k = 0; k < 16; ++k) {
        g0[k] = __uint_as_float(__builtin_amdgcn_readlane(__float_as_uint(gvv), k));
        g1[k] = __uint_as_float(__builtin_amdgcn_readlane(__float_as_uint(gvv), k + 16));
    }

    // ---- direct per-lane x/y rows (36B AoS; wave covers contiguous 2304B, L1-served) ----
    const float* xr = x + ((size_t)nw * 64 + lane) * 9;
    const float* yr = y + ((size_t)nw * 64 + lane) * 9;
    float xv0[9], yv0[9], xv1[9], yv1[9];
#pragma unroll
    for (int c = 0; c < 9; ++c) {
        xv0[c] = xr[c];        yv0[c] = yr[c];
        xv1[c] = xr[c + 576];  yv1[c] = yr[c + 576];
    }

#pragma unroll
    for (int l3 = 0; l3 < 3; ++l3) {
        const int d3 = 2 * l3 + 1;

        // ---- phase 1 (per l3 slice): m[j][e] = Σ_k g[j][k] W[l3,e,f,k]; 4x dwordx4 per e ----
        float m0[9], m1[9];
#pragma unroll
        for (int e = 0; e < 9; ++e) {
            const float4* wp = (const float4*)(wt + (((l3 * 9 + e) * 64 + lane) << 4));
            float wv[16];
            *(float4*)(wv + 0)  = wp[0];
            *(float4*)(wv + 4)  = wp[1];
            *(float4*)(wv + 8)  = wp[2];
            *(float4*)(wv + 12) = wp[3];
            float s0 = 0.0f, s1 = 0.0f;
#pragma unroll
            for (int k = 0; k < 16; ++k) {
                s0 = fmaf(g0[k], wv[k], s0);   // g in SGPR: v_fmac with scalar src
                s1 = fmaf(g1[k], wv[k], s1);
            }
            m0[e] = s0; m1[e] = s1;
        }

        // ---- phase 2: tensor product for this l3, both n rows ----
#pragma unroll
        for (int j = 0; j < TPW; ++j) {
            float o[5];
#pragma unroll
            for (int c = 0; c < d3; ++c) o[c] = 0.0f;
#pragma unroll
            for (int l1 = 0; l1 < 3; ++l1) {
#pragma unroll
                for (int l2 = 0; l2 < 3; ++l2) {
                    const int e  = l1 * 3 + l2;
                    const int d1 = 2 * l1 + 1, d2 = 2 * l2 + 1;
                    const float* cgb = cg + (e * 3 + l3) * 125;  // uniform -> s_load
                    float tp[5];
#pragma unroll
                    for (int c = 0; c < d3; ++c) tp[c] = 0.0f;
#pragma unroll
                    for (int a = 0; a < d1; ++a)
#pragma unroll
                        for (int b = 0; b < d2; ++b) {
                            const float pb = (j == 0 ? xv0[l1 * l1 + a] : xv1[l1 * l1 + a])
                                           * (j == 0 ? yv0[l2 * l2 + b] : yv1[l2 * l2 + b]);
#pragma unroll
                            for (int c = 0; c < d3; ++c)
                                tp[c] = fmaf(pb, cgb[a * 25 + b * 5 + c], tp[c]);
                        }
                    const float mm = (j == 0) ? m0[e] : m1[e];
#pragma unroll
                    for (int c = 0; c < d3; ++c) o[c] = fmaf(mm, tp[c], o[c]);
                }
            }
            // stride-9 LDS rows: lane*9 mod 32 banks conflict-free (9 coprime 32)
#pragma unroll
            for (int c = 0; c < d3; ++c)
                so[w][(j * 64 + lane) * 9 + l3 * l3 + c] = o[c];
        }
    }
    __syncthreads();

    // ---- coalesced float4 store of 2 n rows ----
    const float4* sov = (const float4*)so[w];
    float4* od = (float4*)(out + (size_t)nw * 576);
#pragma unroll
    for (int jj = 0; jj < 4; ++jj) od[lane + 64 * jj] = sov[lane + 64 * jj];
    if (lane < 32) od[256 + lane] = sov[256 + lane];
}

extern "C" void kernel_launch(void* const* d_in, const int* in_sizes, int n_in,
                              void* d_out, int out_size, void* d_ws, size_t ws_size,
                              hipStream_t stream) {
    const float* x  = (const float*)d_in[0];
    const float* y  = (const float*)d_in[1];
    const float* r  = (const float*)d_in[2];
    const float* wq = (const float*)d_in[3];
    const float* cg = (const float*)d_in[4];
    float* out = (float*)d_out;
    float* wt  = (float*)d_ws;                 // 110592 B needed

    transpose_w<<<108, 256, 0, stream>>>(wq, wt);
    pairmix_main<<<NTOT / NPB, 256, 0, stream>>>(x, y, r, cg, wt, out);
}